// Round 1
// baseline (550.057 us; speedup 1.0000x reference)
//
#include <hip/hip_runtime.h>

typedef __bf16 bf16x8 __attribute__((ext_vector_type(8)));
typedef float  f32x4  __attribute__((ext_vector_type(4)));
typedef unsigned short us8 __attribute__((ext_vector_type(8)));

__device__ __forceinline__ unsigned short f2bf(float f) {
    union { float f; unsigned u; } c; c.f = f;
    unsigned u = c.u;
    u += 0x7FFFu + ((u >> 16) & 1u);   // RNE; inputs finite
    return (unsigned short)(u >> 16);
}

// async 16B global -> LDS (dest = wave-uniform base + lane*16)
__device__ __forceinline__ void gl2lds16(const void* g, void* l) {
    __builtin_amdgcn_global_load_lds(
        (const __attribute__((address_space(1))) unsigned int*)g,
        (__attribute__((address_space(3))) unsigned int*)l, 16, 0, 0);
}

#define XS    68            // LDS ci-stride in ushorts for WEIGHTS (136B -> 2-way alias, free)
#define WTAP  (128 * XS)    // ushorts per tap in wpad
#define NXP   340           // 10*34 halo pixels (v1 fallback)

// -------- weight pre-transform: OIHW f32 -> padded [tap][co][XS] bf16 --------
__global__ void __launch_bounds__(256) wxform(const float* __restrict__ W,
                                              unsigned short* __restrict__ wpad) {
    int o = blockIdx.x * 256 + threadIdx.x;        // 9*128*68 = 78336
    if (o < 9 * 128 * XS) {
        int tap = o / (128 * XS);
        int r   = o % (128 * XS);
        int co  = r / XS;
        int ci  = r % XS;
        unsigned short v = 0;
        if (ci < 64) v = f2bf(W[co * 576 + ci * 9 + tap]);   // W[co][ci][kh][kw]
        wpad[o] = v;
    }
}

// -------- x pre-transform: [n][ci][h][w] f32 -> [n][h][w][ci] bf16 ----------
// Within each pixel's 128B (8 granules of 16B = 8 ci), granule g is stored at
// slot g ^ (w & 7). This makes the conv kernel's linear global_load_lds land a
// bank-conflict-free layout for its stride-128B ds_read_b128 A-frag reads.
__global__ void __launch_bounds__(256) xpose(const float* __restrict__ x,
                                             unsigned short* __restrict__ xbf) {
    int px = blockIdx.x * 256 + threadIdx.x;   // n*16384 + h*128 + w ; 1,048,576 total
    int n  = px >> 14;
    int hw = px & 16383;
    int sw = px & 7;                            // == w & 7
    const float* src = x + (size_t)n * 1048576 + hw;   // ci stride = 16384 floats
    unsigned short* dst = xbf + (size_t)px * 64;
    #pragma unroll
    for (int g = 0; g < 8; ++g) {
        us8 v;
        #pragma unroll
        for (int j = 0; j < 8; ++j) v[j] = f2bf(src[(g * 8 + j) * 16384]);
        *(us8*)(dst + ((g ^ sw) << 3)) = v;     // 16B store, slot-permuted in-line
    }
}

// ================= v2: conv with pure-async x staging =======================
struct SmemV2 {
    unsigned short x[10 * 34 * 64];  // 43520 B : halo rows, linear, granule-swizzled
    unsigned short w[2][128 * XS];   // 34816 B : double-buffered tap weights
};                                   // 78336 B -> 2 blocks/CU

__global__ void __launch_bounds__(256, 2)
conv_fused2(const unsigned short* __restrict__ xbf,
            const unsigned short* __restrict__ wpad,
            const float* __restrict__ bias,
            float* __restrict__ out)
{
    __shared__ __align__(16) SmemV2 sm;
    __shared__ float red[4];

    const int tid  = threadIdx.x;
    const int wave = tid >> 6;
    const int lane = tid & 63;
    const int lq   = lane >> 4;
    const int lm   = lane & 15;

    const int ct = blockIdx.x;        // 0..3   col tile (32 wide)
    const int rt = blockIdx.y;        // 0..15  row tile (8 tall)
    const int n  = blockIdx.z;        // 0..63  image

    const int h0 = rt * 8;
    const int w0 = ct * 32;

    // ---- async prefetch of tap-0 weights (17 x 1KB chunks, round-robin waves)
    for (int c = wave; c < 17; c += 4)
        gl2lds16(wpad + c * 512 + lane * 8, &sm.w[0][c * 512]);

    // ---- async stage x halo: 10 rows x 4352 B, pure global_load_lds.
    // Rows h>=128 read garbage (mapped ws) -> only feeds pool row 63, discarded.
    // Cols ww=32,33 at ct=3 wrap into next row -> only feed pool col 63, discarded.
    const char* xb = (const char*)xbf;
    for (int r = wave; r < 10; r += 4) {
        const char* src = xb + ((size_t)(n * 128 + h0 + r) * 128 + w0) * 128;
        char* dst = (char*)sm.x + r * 4352;
        #pragma unroll
        for (int c = 0; c < 4; ++c)
            gl2lds16(src + c * 1024 + lane * 16, dst + c * 1024);
        // 256B tail: full-wave 1KB copy overlapping bytes 3328..4351 (re-writes
        // 3328..4095 with identical data — benign, avoids exec-masked gl2lds)
        gl2lds16(src + 3328 + lane * 16, dst + 3328);
    }

    // bias preload (co = nt*16 + lm)
    float bv[8];
    #pragma unroll
    for (int nt = 0; nt < 8; ++nt) bv[nt] = bias[nt * 16 + lm];

    f32x4 acc[4][8];                  // [rl*2+ch][nt] : 128 VGPRs
    #pragma unroll
    for (int mt = 0; mt < 4; ++mt)
        #pragma unroll
        for (int nt = 0; nt < 8; ++nt)
            acc[mt][nt] = (f32x4){0.f, 0.f, 0.f, 0.f};

    __syncthreads();   // drains all gl2lds (x halo + tap0 weights)

    // ---- K loop: 9 taps, weights double-buffered, ONE barrier per tap ----
    for (int tap = 0; tap < 9; ++tap) {
        const int cur = tap & 1;
        if (tap < 8) {                // prefetch tap+1 into other buffer
            const unsigned short* wt = wpad + (tap + 1) * WTAP;
            for (int c = wave; c < 17; c += 4)
                gl2lds16(wt + c * 512 + lane * 8, &sm.w[cur ^ 1][c * 512]);
        }
        const int kh = tap / 3, kw = tap - kh * 3;

        // A frags: A[m=lm][k=lq*8+j]; swizzled granule read, 16B-aligned
        bf16x8 a[2][2][2];            // [rl][ch][kc]
        #pragma unroll
        for (int rl = 0; rl < 2; ++rl)
            #pragma unroll
            for (int ch = 0; ch < 2; ++ch)
                #pragma unroll
                for (int kc = 0; kc < 2; ++kc) {
                    int ww = ch * 16 + lm + kw;
                    int px = (2 * wave + rl + kh) * 34 + ww;
                    int g4 = ((kc << 2) | lq) ^ (ww & 7);
                    a[rl][ch][kc] = *(const bf16x8*)((const char*)sm.x + px * 128 + g4 * 16);
                }
        #pragma unroll
        for (int nt = 0; nt < 8; ++nt) {
            #pragma unroll
            for (int kc = 0; kc < 2; ++kc) {
                bf16x8 b = *(const bf16x8*)&sm.w[cur][(nt * 16 + lm) * XS + kc * 32 + lq * 8];
                #pragma unroll
                for (int rl = 0; rl < 2; ++rl)
                    #pragma unroll
                    for (int ch = 0; ch < 2; ++ch)
                        acc[rl * 2 + ch][nt] = __builtin_amdgcn_mfma_f32_16x16x32_bf16(
                            a[rl][ch][kc], b, acc[rl * 2 + ch][nt], 0, 0, 0);
            }
        }
        __syncthreads();  // all waves done with w[cur]; drains prefetch into w[cur^1]
    }

    // ---- in-register epilogue (identical to verified v1) ----
    float part = 0.0f;
    const int ph = rt * 4 + wave;                 // pool row (wave-uniform)
    if (ph < 63) {
        #pragma unroll
        for (int ch = 0; ch < 2; ++ch) {
            const int pwb = ct * 16 + ch * 8 + lq * 2;
            #pragma unroll
            for (int nt = 0; nt < 8; ++nt) {
                f32x4 s = acc[ch][nt] + acc[2 + ch][nt];   // vertical pool sum
                float p0 = s[0] + s[1];
                float p1 = s[2] + s[3];
                float bb = bv[nt];
                if (pwb < 63) {
                    float v = 0.25f * p0 + bb;
                    part += 1.0f / (1.0f + __expf(-v));
                }
                if (pwb + 1 < 63) {
                    float v = 0.25f * p1 + bb;
                    part += 1.0f / (1.0f + __expf(-v));
                }
            }
        }
    }

    #pragma unroll
    for (int off = 32; off > 0; off >>= 1)
        part += __shfl_down(part, off, 64);
    if (lane == 0) red[wave] = part;
    __syncthreads();
    if (tid == 0) atomicAdd(&out[n], red[0] + red[1] + red[2] + red[3]);
}

// ================= v1 fallback: verified 478.7 µs kernel ====================
struct SmemT {
    unsigned short x[NXP * XS];      // 46240 B : halo [px][ci] bf16
    unsigned short w[2][128 * XS];   // 34816 B
};

__global__ void __launch_bounds__(256, 2)
conv_fused(const float* __restrict__ x,
           const unsigned short* __restrict__ wpad,
           const float* __restrict__ bias,
           float* __restrict__ out)
{
    __shared__ __align__(16) SmemT sm;
    __shared__ float red[4];

    const int tid  = threadIdx.x;
    const int wave = tid >> 6;
    const int lane = tid & 63;
    const int lq   = lane >> 4;
    const int lm   = lane & 15;

    const int ct = blockIdx.x;
    const int rt = blockIdx.y;
    const int n  = blockIdx.z;

    const int h0 = rt * 8;
    const int w0 = ct * 32;
    const float* xn = x + (size_t)n * (64u * 128u * 128u);

    for (int c = wave; c < 17; c += 4)
        gl2lds16(wpad + c * 512 + lane * 8, &sm.w[0][c * 512]);

    for (int it = 0; it < 11; ++it) {
        int t = tid + it * 256;
        if (t < NXP * 8) {
            int px = t % NXP;
            int g  = t / NXP;
            int hh = px / 34, ww = px % 34;
            int h = h0 + hh, w = w0 + ww;
            bool ok = (h < 128) && (w < 128);
            const float* src = xn + (size_t)(g * 8) * 16384 + h * 128 + w;
            us8 v;
            #pragma unroll
            for (int j = 0; j < 8; ++j) {
                float f = ok ? src[j * 16384] : 0.0f;
                v[j] = f2bf(f);
            }
            *(us8*)&sm.x[px * XS + g * 8] = v;
        }
    }

    float bv[8];
    #pragma unroll
    for (int nt = 0; nt < 8; ++nt) bv[nt] = bias[nt * 16 + lm];

    f32x4 acc[4][8];
    #pragma unroll
    for (int mt = 0; mt < 4; ++mt)
        #pragma unroll
        for (int nt = 0; nt < 8; ++nt)
            acc[mt][nt] = (f32x4){0.f, 0.f, 0.f, 0.f};

    __syncthreads();

    for (int tap = 0; tap < 9; ++tap) {
        const int cur = tap & 1;
        if (tap < 8) {
            const unsigned short* wt = wpad + (tap + 1) * WTAP;
            for (int c = wave; c < 17; c += 4)
                gl2lds16(wt + c * 512 + lane * 8, &sm.w[cur ^ 1][c * 512]);
        }
        const int kh = tap / 3, kw = tap - kh * 3;

        bf16x8 a[2][2][2];
        #pragma unroll
        for (int rl = 0; rl < 2; ++rl)
            #pragma unroll
            for (int ch = 0; ch < 2; ++ch)
                #pragma unroll
                for (int kc = 0; kc < 2; ++kc) {
                    int px = (2 * wave + rl + kh) * 34 + ch * 16 + lm + kw;
                    a[rl][ch][kc] = *(const bf16x8*)&sm.x[px * XS + kc * 32 + lq * 8];
                }
        #pragma unroll
        for (int nt = 0; nt < 8; ++nt) {
            #pragma unroll
            for (int kc = 0; kc < 2; ++kc) {
                bf16x8 b = *(const bf16x8*)&sm.w[cur][(nt * 16 + lm) * XS + kc * 32 + lq * 8];
                #pragma unroll
                for (int rl = 0; rl < 2; ++rl)
                    #pragma unroll
                    for (int ch = 0; ch < 2; ++ch)
                        acc[rl * 2 + ch][nt] = __builtin_amdgcn_mfma_f32_16x16x32_bf16(
                            a[rl][ch][kc], b, acc[rl * 2 + ch][nt], 0, 0, 0);
            }
        }
        __syncthreads();
    }

    float part = 0.0f;
    const int ph = rt * 4 + wave;
    if (ph < 63) {
        #pragma unroll
        for (int ch = 0; ch < 2; ++ch) {
            const int pwb = ct * 16 + ch * 8 + lq * 2;
            #pragma unroll
            for (int nt = 0; nt < 8; ++nt) {
                f32x4 s = acc[ch][nt] + acc[2 + ch][nt];
                float p0 = s[0] + s[1];
                float p1 = s[2] + s[3];
                float bb = bv[nt];
                if (pwb < 63) {
                    float v = 0.25f * p0 + bb;
                    part += 1.0f / (1.0f + __expf(-v));
                }
                if (pwb + 1 < 63) {
                    float v = 0.25f * p1 + bb;
                    part += 1.0f / (1.0f + __expf(-v));
                }
            }
        }
    }

    #pragma unroll
    for (int off = 32; off > 0; off >>= 1)
        part += __shfl_down(part, off, 64);
    if (lane == 0) red[wave] = part;
    __syncthreads();
    if (tid == 0) atomicAdd(&out[n], red[0] + red[1] + red[2] + red[3]);
}

extern "C" void kernel_launch(void* const* d_in, const int* in_sizes, int n_in,
                              void* d_out, int out_size, void* d_ws, size_t ws_size,
                              hipStream_t stream) {
    const float* x = (const float*)d_in[0];
    const float* W = (const float*)d_in[1];
    const float* b = (const float*)d_in[2];
    float* out = (float*)d_out;

    const size_t WOFF   = 138412032ull;                      // 132 MiB (x' is 128 MiB + OOB slack)
    const size_t NEEDED = WOFF + (size_t)(9 * 128 * XS) * 2; // + 156,672 B wpad

    hipMemsetAsync(d_out, 0, 64 * sizeof(float), stream);

    if (ws_size >= NEEDED) {
        unsigned short* xbf  = (unsigned short*)d_ws;
        unsigned short* wpad = (unsigned short*)((char*)d_ws + WOFF);
        wxform<<<(9 * 128 * XS + 255) / 256, 256, 0, stream>>>(W, wpad);
        xpose<<<4096, 256, 0, stream>>>(x, xbf);
        conv_fused2<<<dim3(4, 16, 64), 256, 0, stream>>>(xbf, wpad, b, out);
    } else {
        unsigned short* wpad = (unsigned short*)d_ws;
        wxform<<<(9 * 128 * XS + 255) / 256, 256, 0, stream>>>(W, wpad);
        conv_fused<<<dim3(4, 16, 64), 256, 0, stream>>>(x, wpad, b, out);
    }
}